// Round 5
// baseline (316.216 us; speedup 1.0000x reference)
//
#include <hip/hip_runtime.h>
#include <math.h>

#define KQ   32768
#define CC   100
#define BB   1024
#define DD   128
#define NTOT (BB + KQ)        // 33792
#define CB_CENT 1056
#define NCB  1060             // 32-row blocks in X2
#define NHIST 33              // histogram blocks (33*1024 = 33792)
#define NCG2 132              // branch-2 col groups (8 cb each)
#define NCG  141              // + 9 branch-1 col groups (4 cb each)
#define NACT 1136             // active gemm blocks: (141 + 1 sup) * 8 rt

#define INV_T  14.285714285714286f
#define ALPHA  0.05f
#define EPSV   1e-12f

typedef __attribute__((ext_vector_type(8)))  short          short8;
typedef __attribute__((ext_vector_type(8)))  unsigned short ushort8;
typedef __attribute__((ext_vector_type(16))) float          float16;

__device__ __forceinline__ unsigned short f2bf_rne(float f) {
    unsigned int u = __float_as_uint(f);
    return (unsigned short)((u + 0x7FFFu + ((u >> 16) & 1u)) >> 16);
}

// X2 layout per 32-row block cb (16384 B): [hi 8KB | lo 8KB][ks 0..7][lane 0..63][16 B]
// element (row r, k): cb=r>>5, ks=k>>4, lane=(r&31)+32*((k>>3)&1), j=k&7
// == 32x32x16 MFMA A/B operand layout (verified R2-R4, absmax 0).

// ---------------- prep: convert+tile + parallel histogram ----------------
__global__ __launch_bounds__(256) void prep_k(const float* __restrict__ feats,
                                              const float* __restrict__ centers,
                                              const int* __restrict__ labels,
                                              unsigned short* __restrict__ X2,
                                              int* __restrict__ cntAll,
                                              int* __restrict__ cntBatch) {
    const int b = blockIdx.x, t = threadIdx.x;
    if (b >= NCB) {  // histogram blocks: LDS-local then one global atomic per bin
        __shared__ int hA[CC], hB[CC];
        if (t < CC) { hA[t] = 0; hB[t] = 0; }
        __syncthreads();
        const int base = (b - NCB) * 1024;
#pragma unroll
        for (int q = 0; q < 4; ++q) {
            int idx = base + q * 256 + t;
            int l = labels[idx];
            atomicAdd(&hA[l], 1);
            if (idx < BB) atomicAdd(&hB[l], 1);
        }
        __syncthreads();
        if (t < CC) {
            if (hA[t]) atomicAdd(&cntAll[t], hA[t]);
            if (hB[t]) atomicAdd(&cntBatch[t], hB[t]);
        }
        return;
    }
    __shared__ unsigned short sm[8192];
    const int row = t >> 3, seg = t & 7;
    const int r = b * 32 + row;
    float v[16];
    if (r < NTOT) {
        const float4* p = (const float4*)&feats[(size_t)r * DD + seg * 16];
#pragma unroll
        for (int j = 0; j < 4; ++j) { float4 q = p[j]; v[4*j]=q.x; v[4*j+1]=q.y; v[4*j+2]=q.z; v[4*j+3]=q.w; }
    } else if (r < NTOT + CC) {
        const float4* p = (const float4*)&centers[(size_t)(r - NTOT) * DD + seg * 16];
#pragma unroll
        for (int j = 0; j < 4; ++j) { float4 q = p[j]; v[4*j]=q.x; v[4*j+1]=q.y; v[4*j+2]=q.z; v[4*j+3]=q.w; }
    } else {
#pragma unroll
        for (int j = 0; j < 16; ++j) v[j] = 0.f;
    }
    ushort8 H0, H1, L0, L1;
#pragma unroll
    for (int m = 0; m < 8; ++m) {
        unsigned short hb = f2bf_rne(v[m]);
        float hf = __uint_as_float(((unsigned int)hb) << 16);
        H0[m] = hb; L0[m] = f2bf_rne(v[m] - hf);
        unsigned short hb2 = f2bf_rne(v[m + 8]);
        float hf2 = __uint_as_float(((unsigned int)hb2) << 16);
        H1[m] = hb2; L1[m] = f2bf_rne(v[m + 8] - hf2);
    }
    *(ushort8*)&sm[seg * 512 + row * 8]               = H0;
    *(ushort8*)&sm[seg * 512 + (row + 32) * 8]        = H1;
    *(ushort8*)&sm[4096 + seg * 512 + row * 8]        = L0;
    *(ushort8*)&sm[4096 + seg * 512 + (row + 32) * 8] = L1;
    __syncthreads();
    const ushort8* src = (const ushort8*)sm;
    ushort8* dst = (ushort8*)((char*)X2 + (size_t)b * 16384);
#pragma unroll
    for (int j = 0; j < 4; ++j) dst[j * 256 + t] = src[j * 256 + t];
}

// ---------------- async stage one 16 KB B-block into LDS ----------------
__device__ __forceinline__ void stage_cb(const char* Xb, int cb, char* dst,
                                         int w, int lane) {
    const char* g = Xb + (size_t)cb * 16384 + (size_t)(w * 4096 + lane * 16);
    char* lp = dst + w * 4096;   // wave-uniform LDS base; HW scatters lane*16
#pragma unroll
    for (int c = 0; c < 4; ++c)
        __builtin_amdgcn_global_load_lds(
            (const __attribute__((address_space(1))) unsigned int*)(g + c * 1024),
            (__attribute__((address_space(3))) unsigned int*)(lp + c * 1024),
            16, 0, 0);
}

// ---------------- compute one 32x32 tile from an LDS-staged B block ----------------
__device__ __forceinline__ void compute_tile(
    const char* buf, int cb, int lc, float rn, float drm, bool checkDiag,
    int lane, int half, int ln, int growbase,
    const short8* Ah, const short8* Al, const int* rlab,
    float* sS, float* sN)
{
    const char* bp = buf + lane * 16;
    float16 acc;
#pragma unroll
    for (int reg = 0; reg < 16; ++reg) acc[reg] = 0.f;
#pragma unroll
    for (int ks = 0; ks < 8; ++ks) {
        short8 Bh = *(const short8*)(bp + ks * 1024);
        short8 Bl = *(const short8*)(bp + 8192 + ks * 1024);
        acc = __builtin_amdgcn_mfma_f32_32x32x16_bf16(Ah[ks], Bh, acc, 0, 0, 0);
        acc = __builtin_amdgcn_mfma_f32_32x32x16_bf16(Ah[ks], Bl, acc, 0, 0, 0);
        acc = __builtin_amdgcn_mfma_f32_32x32x16_bf16(Al[ks], Bh, acc, 0, 0, 0);
    }
    const int ccol = cb * 32 + ln;
#pragma unroll
    for (int reg = 0; reg < 16; ++reg) {
        int ro = (reg & 3) + 8 * (reg >> 2) + 4 * half;
        float a  = acc[reg];
        float mf = (lc == rlab[reg]) ? 1.f : 0.f;
        float wgt = fmaf(mf, drm, rn);
        if (checkDiag) {              // wave-uniform; at most 1 of 8 cb iters
            bool d = (ccol == growbase + ro);
            wgt = d ? 0.f : wgt;
            mf  = d ? 0.f : mf;
        }
        float e = __expf(fmaf(a, INV_T, -INV_T));
        sS[reg] = fmaf(e, wgt, sS[reg]);
        sN[reg] = fmaf(mf, a, sN[reg]);   // un-scaled dot; *INV_T at finalize
    }
}

// ---------------- fused GEMM + sup-sums + last-block finalize ----------------
// grid 1152 = 8 xcd * 18 ci * 8 rt; cg = xcd + 8*ci.
// cg<132: branch2 (8 cb). 132..140: branch1 (4 cb). 141: sup sums. >141: idle.
__global__ __launch_bounds__(256, 3) void gemm_k(
    const unsigned short* __restrict__ X2, const int* __restrict__ labels,
    const int* __restrict__ cntAll, const int* __restrict__ cntBatch,
    const float* __restrict__ sup, float* __restrict__ acc4,
    float* __restrict__ aLi, unsigned int* __restrict__ ticket,
    float* __restrict__ out) {
    const int b = blockIdx.x;
    const int xcd = b & 7, l = b >> 3;
    const int rt = l & 7, ci = l >> 3;
    const int cg = xcd + 8 * ci;
    if (cg > NCG) return;

    const int tid = threadIdx.x;
    const int lane = tid & 63, w = tid >> 6;
    const int half = lane >> 5, ln = lane & 31;
    const char* Xb = (const char*)X2;
    __shared__ char sm[32768];   // double-buffered 16 KB B blocks

    if (cg < NCG) {
        const int rb = rt * 4 + w;
        const int growbase = rt * 128 + w * 32;
        short8 Ah[8], Al[8];
        {
            size_t abase = (size_t)rb * 16384 + (size_t)lane * 16;
#pragma unroll
            for (int ks = 0; ks < 8; ++ks) {
                Ah[ks] = *(const short8*)(Xb + abase + (size_t)ks * 1024);
                Al[ks] = *(const short8*)(Xb + abase + 8192 + (size_t)ks * 1024);
            }
        }
        int rlab[16];
#pragma unroll
        for (int reg = 0; reg < 16; ++reg) {
            int ro = (reg & 3) + 8 * (reg >> 2) + 4 * half;
            rlab[reg] = labels[growbase + ro];
        }
        float sS[16], sN[16];
#pragma unroll
        for (int reg = 0; reg < 16; ++reg) { sS[reg] = 0.f; sN[reg] = 0.f; }

        const bool isB2 = (cg < NCG2);
        if (isB2) {
            const int cb0 = cg * 8;
            stage_cb(Xb, cb0, sm, w, lane);
            __syncthreads();
#pragma unroll
            for (int i = 0; i < 8; ++i) {
                const int cb = cb0 + i;
                if (i < 7) stage_cb(Xb, cb + 1, sm + 16384 * ((i + 1) & 1), w, lane);
                int lc = labels[cb * 32 + ln];
                float c = (float)cntAll[lc];
                float rn = __builtin_amdgcn_rcpf(c);
                float drm = __builtin_amdgcn_rcpf(c - ALPHA) - rn;
                compute_tile(sm + 16384 * (i & 1), cb, lc, rn, drm, cb == rb,
                             lane, half, ln, growbase, Ah, Al, rlab, sS, sN);
                __syncthreads();
            }
        } else {
            const int t1 = cg - NCG2;
            int cbs[4];
#pragma unroll
            for (int i = 0; i < 4; ++i) cbs[i] = (t1 < 8) ? (t1 * 4 + i) : (CB_CENT + i);
            stage_cb(Xb, cbs[0], sm, w, lane);
            __syncthreads();
#pragma unroll
            for (int i = 0; i < 4; ++i) {
                const int cb = cbs[i];
                if (i < 3) stage_cb(Xb, cbs[i + 1], sm + 16384 * ((i + 1) & 1), w, lane);
                int ccol = cb * 32 + ln;
                int lc;
                if (t1 < 8) lc = labels[ccol];
                else { int c2 = ccol - NTOT; lc = (c2 < CC) ? c2 : -1; }
                int cbv = (lc >= 0) ? cntBatch[lc] : 0;
                float c1 = (float)(cbv + 1);
                float rn = (lc >= 0) ? __builtin_amdgcn_rcpf(c1) : 0.f;
                float rm = __builtin_amdgcn_rcpf(fmaxf(c1 - 1.f, 1.f));
                float drm = (lc >= 0) ? (rm - rn) : 0.f;
                compute_tile(sm + 16384 * (i & 1), cb, lc, rn, drm,
                             (t1 < 8) && (cb == rb),
                             lane, half, ln, growbase, Ah, Al, rlab, sS, sN);
                __syncthreads();
            }
        }
        float* aS = isB2 ? acc4          : (acc4 + 2048);
        float* aN = isB2 ? (acc4 + 1024) : (acc4 + 3072);
#pragma unroll
        for (int reg = 0; reg < 16; ++reg) {
            float a = sS[reg], c = sN[reg];
#pragma unroll
            for (int off = 1; off < 32; off <<= 1) {
                a += __shfl_xor(a, off, 64);
                c += __shfl_xor(c, off, 64);
            }
            if (ln == 0) {
                int ro = (reg & 3) + 8 * (reg >> 2) + 4 * half;
                int grow = growbase + ro;
                atomicAdd(&aS[grow], a);
                atomicAdd(&aN[grow], c);
            }
        }
    } else {
        // cg == 141: sup-logits exp-sums, coalesced (lane = class), wave = 32 rows
        const int g = rt * 4 + w;
        const int c0 = lane;
        const int c1 = lane + 64;
        float n0 = (float)cntAll[c0];
        float rA0 = __builtin_amdgcn_rcpf(n0);
        float rAm0 = __builtin_amdgcn_rcpf(fmaxf(n0 - 1.f, 1.f));
        float rA1 = 0.f, rAm1 = 0.f;
        if (lane < 36) {
            float n1 = (float)cntAll[c1];
            rA1 = __builtin_amdgcn_rcpf(n1);
            rAm1 = __builtin_amdgcn_rcpf(fmaxf(n1 - 1.f, 1.f));
        }
        for (int rr = 0; rr < 32; ++rr) {
            int row = g * 32 + rr;
            int li = labels[row];
            const float* srow = &sup[(size_t)row * CC];
            float v0 = srow[c0];
            float s = __expf(v0 - INV_T) * ((c0 == li) ? rAm0 : rA0);
            float liv = (c0 == li) ? v0 : 0.f;
            if (lane < 36) {
                float v1 = srow[c1];
                s += __expf(v1 - INV_T) * ((c1 == li) ? rAm1 : rA1);
                liv += (c1 == li) ? v1 : 0.f;
            }
#pragma unroll
            for (int off = 1; off < 64; off <<= 1) {
                s += __shfl_xor(s, off, 64);
                liv += __shfl_xor(liv, off, 64);
            }
            if (lane == 0) {
                atomicAdd(&acc4[row], s);
                atomicAdd(&aLi[row], liv);
            }
        }
    }

    // ---------------- ticket: last active block finalizes ----------------
    __syncthreads();
    __threadfence();
    __shared__ unsigned int lastFlag;
    if (tid == 0) {
        unsigned int old = __hip_atomic_fetch_add(ticket, 1u, __ATOMIC_ACQ_REL,
                                                  __HIP_MEMORY_SCOPE_AGENT);
        lastFlag = (old == NACT - 1) ? 1u : 0u;
    }
    __syncthreads();
    if (!lastFlag) return;
    __threadfence();

    float lsum = 0.f;
#pragma unroll
    for (int q = 0; q < 4; ++q) {
        int row = q * 256 + tid;
        int li = labels[row];
        float S2 = acc4[row];
        float N2 = acc4[1024 + row] * INV_T;
        float S1 = acc4[2048 + row];
        float N1v = acc4[3072 + row] * INV_T;
        float sli = aLi[row];
        float cA = (float)cntAll[li];
        float msum2 = fmaf(ALPHA, cA - 1.f, 1.f);
        float loss2 = -(fmaf(ALPHA, N2, sli) / msum2 - INV_T - logf(S2 + EPSV));
        float loss1 = -(N1v / (float)cntBatch[li] - INV_T - logf(S1 + EPSV));
        lsum += loss1 + loss2;
    }
    __shared__ float rbuf[4];
#pragma unroll
    for (int off = 1; off < 64; off <<= 1) lsum += __shfl_xor(lsum, off, 64);
    if (lane == 0) rbuf[w] = lsum;
    __syncthreads();
    if (tid == 0) out[0] = (rbuf[0] + rbuf[1] + rbuf[2] + rbuf[3]) / (float)BB;
}

extern "C" void kernel_launch(void* const* d_in, const int* in_sizes, int n_in,
                              void* d_out, int out_size, void* d_ws, size_t ws_size,
                              hipStream_t stream) {
    const float* feats   = (const float*)d_in[0];
    const float* sup     = (const float*)d_in[1];
    const float* centers = (const float*)d_in[2];
    const int*   labels  = (const int*)d_in[3];
    float* out = (float*)d_out;
    char*  wsb = (char*)d_ws;

    const size_t X2_BYTES = (size_t)NCB * 16384;        // 17,367,040
    unsigned short* X2 = (unsigned short*)wsb;
    char* base2 = wsb + X2_BYTES;
    int* cntAll   = (int*)base2;                        // 128 ints (padded 512 B)
    int* cntBatch = cntAll + 128;                       // 512 B
    float* acc4   = (float*)(base2 + 1024);             // 4*1024: S2,N2,S1,N1
    float* aLi    = acc4 + 4096;                        // 1024
    unsigned int* ticket = (unsigned int*)(aLi + 1024); // 1

    hipMemsetAsync(base2, 0, 1024 + 16384 + 4096 + 4, stream);
    prep_k<<<NCB + NHIST, 256, 0, stream>>>(feats, centers, labels, X2, cntAll, cntBatch);
    gemm_k<<<8 * 18 * 8, 256, 0, stream>>>(X2, labels, cntAll, cntBatch, sup,
                                           acc4, aLi, ticket, out);
}

// Round 6
// 217.352 us; speedup vs baseline: 1.4549x; 1.4549x over previous
//
#include <hip/hip_runtime.h>
#include <math.h>

#define KQ   32768
#define CC   100
#define BB   1024
#define DD   128
#define NTOT (BB + KQ)        // 33792
#define CB_CENT 1056
#define NCB  1060             // 32-row blocks in X2
#define NHIST 33              // histogram blocks (33*1024 = 33792)
#define NCG2 132              // branch-2 col groups (8 cb each)
#define NCG  141              // + 9 branch-1 col groups (4 cb each)
#define NACT 1136             // active gemm blocks: (141 + 1 sup) * 8 rt

#define INV_T  14.285714285714286f
#define K2E    20.609929f     // INV_T * log2(e)
#define ALPHA  0.05f
#define EPSV   1e-12f

typedef __attribute__((ext_vector_type(8)))  short          short8;
typedef __attribute__((ext_vector_type(8)))  unsigned short ushort8;
typedef __attribute__((ext_vector_type(16))) float          float16;

__device__ __forceinline__ unsigned short f2bf_rne(float f) {
    unsigned int u = __float_as_uint(f);
    return (unsigned short)((u + 0x7FFFu + ((u >> 16) & 1u)) >> 16);
}

// X2 layout per 32-row block cb (8192 B): [ks 0..7][lane 0..63][16 B]
// element (row r, k): cb=r>>5, ks=k>>4, lane=(r&31)+32*((k>>3)&1), j=k&7
// == 32x32x16 MFMA A/B operand layout (verified R2-R5; now bf16-only).

// ---------------- prep: convert+tile + parallel histogram ----------------
__global__ __launch_bounds__(256) void prep_k(const float* __restrict__ feats,
                                              const float* __restrict__ centers,
                                              const int* __restrict__ labels,
                                              unsigned short* __restrict__ X2,
                                              int* __restrict__ cntAll,
                                              int* __restrict__ cntBatch) {
    const int b = blockIdx.x, t = threadIdx.x;
    if (b >= NCB) {  // histogram blocks: LDS-local then one global atomic per bin
        __shared__ int hA[CC], hB[CC];
        if (t < CC) { hA[t] = 0; hB[t] = 0; }
        __syncthreads();
        const int base = (b - NCB) * 1024;
#pragma unroll
        for (int q = 0; q < 4; ++q) {
            int idx = base + q * 256 + t;
            int l = labels[idx];
            atomicAdd(&hA[l], 1);
            if (idx < BB) atomicAdd(&hB[l], 1);
        }
        __syncthreads();
        if (t < CC) {
            if (hA[t]) atomicAdd(&cntAll[t], hA[t]);
            if (hB[t]) atomicAdd(&cntBatch[t], hB[t]);
        }
        return;
    }
    __shared__ unsigned short sm[4096];   // 8 KB staging, layout == output block
    const int row = t >> 3, seg = t & 7;
    const int r = b * 32 + row;
    float v[16];
    if (r < NTOT) {
        const float4* p = (const float4*)&feats[(size_t)r * DD + seg * 16];
#pragma unroll
        for (int j = 0; j < 4; ++j) { float4 q = p[j]; v[4*j]=q.x; v[4*j+1]=q.y; v[4*j+2]=q.z; v[4*j+3]=q.w; }
    } else if (r < NTOT + CC) {
        const float4* p = (const float4*)&centers[(size_t)(r - NTOT) * DD + seg * 16];
#pragma unroll
        for (int j = 0; j < 4; ++j) { float4 q = p[j]; v[4*j]=q.x; v[4*j+1]=q.y; v[4*j+2]=q.z; v[4*j+3]=q.w; }
    } else {
#pragma unroll
        for (int j = 0; j < 16; ++j) v[j] = 0.f;
    }
    ushort8 H0, H1;
#pragma unroll
    for (int m = 0; m < 8; ++m) {
        H0[m] = f2bf_rne(v[m]);
        H1[m] = f2bf_rne(v[m + 8]);
    }
    // halfword index: ks*512 + lane*8 + j
    *(ushort8*)&sm[seg * 512 + row * 8]        = H0;
    *(ushort8*)&sm[seg * 512 + (row + 32) * 8] = H1;
    __syncthreads();
    const ushort8* src = (const ushort8*)sm;
    ushort8* dst = (ushort8*)((char*)X2 + (size_t)b * 8192);
#pragma unroll
    for (int j = 0; j < 2; ++j) dst[j * 256 + t] = src[j * 256 + t];
}

// ---------------- fused GEMM + sup-sums + last-block finalize ----------------
// grid 1152 = 8 xcd * 8 rt * 18 ci; cg = xcd + 8*ci.
// cg<132: branch2 (8 cb). 132..140: branch1 (4 cb). 141: sup sums. >141: idle.
__global__ __launch_bounds__(256) void gemm_k(
    const unsigned short* __restrict__ X2, const int* __restrict__ labels,
    const int* __restrict__ cntAll, const int* __restrict__ cntBatch,
    const float* __restrict__ sup, float* __restrict__ acc4,
    float* __restrict__ aLi, unsigned int* __restrict__ ticket,
    float* __restrict__ out) {
    const int b = blockIdx.x;
    const int xcd = b & 7, l = b >> 3;
    const int rt = l & 7, ci = l >> 3;
    const int cg = xcd + 8 * ci;
    if (cg > NCG) return;

    const int tid = threadIdx.x;
    const int lane = tid & 63, w = tid >> 6;
    const int half = lane >> 5, ln = lane & 31;
    const char* Xb = (const char*)X2;

    if (cg < NCG) {
        const int rb = rt * 4 + w;
        const int growbase = rt * 128 + w * 32;
        short8 Ah[8];
        {
            size_t abase = (size_t)rb * 8192 + (size_t)lane * 16;
#pragma unroll
            for (int ks = 0; ks < 8; ++ks)
                Ah[ks] = *(const short8*)(Xb + abase + (size_t)ks * 1024);
        }
        int rlab[16];
#pragma unroll
        for (int reg = 0; reg < 16; ++reg) {
            int ro = (reg & 3) + 8 * (reg >> 2) + 4 * half;
            rlab[reg] = labels[growbase + ro];
        }
        float sS[16], sN[16];
#pragma unroll
        for (int reg = 0; reg < 16; ++reg) { sS[reg] = 0.f; sN[reg] = 0.f; }

        const bool isB2 = (cg < NCG2);
        const int t1 = cg - NCG2;
        const int ncb = isB2 ? 8 : 4;
#pragma unroll 4
        for (int i = 0; i < ncb; ++i) {
            int cb;
            if (isB2)          cb = cg * 8 + i;
            else if (t1 < 8)   cb = t1 * 4 + i;
            else               cb = CB_CENT + i;
            const int ccol = cb * 32 + ln;
            int lc; float rn, drm;
            if (isB2) {
                lc = labels[ccol];
                float c = (float)cntAll[lc];
                rn = __builtin_amdgcn_rcpf(c);
                drm = __builtin_amdgcn_rcpf(c - ALPHA) - rn;
            } else {
                if (t1 < 8) lc = labels[ccol];
                else { int c2 = ccol - NTOT; lc = (c2 < CC) ? c2 : -1; }
                int cbv = (lc >= 0) ? cntBatch[lc] : 0;
                float c1 = (float)(cbv + 1);
                rn = (lc >= 0) ? __builtin_amdgcn_rcpf(c1) : 0.f;
                float rm = __builtin_amdgcn_rcpf(fmaxf(c1 - 1.f, 1.f));
                drm = (lc >= 0) ? (rm - rn) : 0.f;
            }
            const size_t bbase = (size_t)cb * 8192 + (size_t)lane * 16;
            float16 acc;
#pragma unroll
            for (int reg = 0; reg < 16; ++reg) acc[reg] = 0.f;
#pragma unroll
            for (int ks = 0; ks < 8; ++ks) {
                short8 Bh = *(const short8*)(Xb + bbase + (size_t)ks * 1024);
                acc = __builtin_amdgcn_mfma_f32_32x32x16_bf16(Ah[ks], Bh, acc, 0, 0, 0);
            }
            const bool checkDiag = (cb == rb) && (isB2 || t1 < 8);  // wave-uniform
#pragma unroll
            for (int reg = 0; reg < 16; ++reg) {
                int ro = (reg & 3) + 8 * (reg >> 2) + 4 * half;
                float a  = acc[reg];
                float mf = (lc == rlab[reg]) ? 1.f : 0.f;
                float wgt = fmaf(mf, drm, rn);
                if (checkDiag) {
                    bool d = (ccol == growbase + ro);
                    wgt = d ? 0.f : wgt;
                    mf  = d ? 0.f : mf;
                }
                float e = exp2f(fmaf(a, K2E, -K2E));   // exp(raw - SHIFT)
                sS[reg] = fmaf(e, wgt, sS[reg]);
                sN[reg] = fmaf(mf, a, sN[reg]);        // un-scaled dot; *INV_T later
            }
        }
        float* aS = isB2 ? acc4          : (acc4 + 2048);
        float* aN = isB2 ? (acc4 + 1024) : (acc4 + 3072);
#pragma unroll
        for (int reg = 0; reg < 16; ++reg) {
            float a = sS[reg], c = sN[reg];
#pragma unroll
            for (int off = 1; off < 32; off <<= 1) {
                a += __shfl_xor(a, off, 64);
                c += __shfl_xor(c, off, 64);
            }
            if (ln == 0) {
                int ro = (reg & 3) + 8 * (reg >> 2) + 4 * half;
                int grow = growbase + ro;
                atomicAdd(&aS[grow], a);
                atomicAdd(&aN[grow], c);
            }
        }
    } else {
        // cg == 141: sup-logits exp-sums, coalesced (lane = class), wave = 32 rows
        const int g = rt * 4 + w;
        const int c0 = lane;
        const int c1 = lane + 64;
        float n0 = (float)cntAll[c0];
        float rA0 = __builtin_amdgcn_rcpf(n0);
        float rAm0 = __builtin_amdgcn_rcpf(fmaxf(n0 - 1.f, 1.f));
        float rA1 = 0.f, rAm1 = 0.f;
        if (lane < 36) {
            float n1 = (float)cntAll[c1];
            rA1 = __builtin_amdgcn_rcpf(n1);
            rAm1 = __builtin_amdgcn_rcpf(fmaxf(n1 - 1.f, 1.f));
        }
        for (int rr = 0; rr < 32; ++rr) {
            int row = g * 32 + rr;
            int li = labels[row];
            const float* srow = &sup[(size_t)row * CC];
            float v0 = srow[c0];
            float s = __expf(v0 - INV_T) * ((c0 == li) ? rAm0 : rA0);
            float liv = (c0 == li) ? v0 : 0.f;
            if (lane < 36) {
                float v1 = srow[c1];
                s += __expf(v1 - INV_T) * ((c1 == li) ? rAm1 : rA1);
                liv += (c1 == li) ? v1 : 0.f;
            }
#pragma unroll
            for (int off = 1; off < 64; off <<= 1) {
                s += __shfl_xor(s, off, 64);
                liv += __shfl_xor(liv, off, 64);
            }
            if (lane == 0) {
                atomicAdd(&acc4[row], s);
                atomicAdd(&aLi[row], liv);
            }
        }
    }

    // ---------------- ticket: last active block finalizes ----------------
    __syncthreads();
    __threadfence();
    __shared__ unsigned int lastFlag;
    if (tid == 0) {
        unsigned int old = __hip_atomic_fetch_add(ticket, 1u, __ATOMIC_ACQ_REL,
                                                  __HIP_MEMORY_SCOPE_AGENT);
        lastFlag = (old == NACT - 1) ? 1u : 0u;
    }
    __syncthreads();
    if (!lastFlag) return;
    __threadfence();

    float lsum = 0.f;
#pragma unroll
    for (int q = 0; q < 4; ++q) {
        int row = q * 256 + tid;
        int li = labels[row];
        float S2 = acc4[row];
        float N2 = acc4[1024 + row] * INV_T;
        float S1 = acc4[2048 + row];
        float N1v = acc4[3072 + row] * INV_T;
        float sli = aLi[row];
        float cA = (float)cntAll[li];
        float msum2 = fmaf(ALPHA, cA - 1.f, 1.f);
        float loss2 = -(fmaf(ALPHA, N2, sli) / msum2 - INV_T - logf(S2 + EPSV));
        float loss1 = -(N1v / (float)cntBatch[li] - INV_T - logf(S1 + EPSV));
        lsum += loss1 + loss2;
    }
    __shared__ float rbuf[4];
#pragma unroll
    for (int off = 1; off < 64; off <<= 1) lsum += __shfl_xor(lsum, off, 64);
    if (lane == 0) rbuf[w] = lsum;
    __syncthreads();
    if (tid == 0) out[0] = (rbuf[0] + rbuf[1] + rbuf[2] + rbuf[3]) / (float)BB;
}

extern "C" void kernel_launch(void* const* d_in, const int* in_sizes, int n_in,
                              void* d_out, int out_size, void* d_ws, size_t ws_size,
                              hipStream_t stream) {
    const float* feats   = (const float*)d_in[0];
    const float* sup     = (const float*)d_in[1];
    const float* centers = (const float*)d_in[2];
    const int*   labels  = (const int*)d_in[3];
    float* out = (float*)d_out;
    char*  wsb = (char*)d_ws;

    const size_t X2_BYTES = (size_t)NCB * 8192;         // 8,683,520
    unsigned short* X2 = (unsigned short*)wsb;
    char* base2 = wsb + X2_BYTES;
    int* cntAll   = (int*)base2;                        // 128 ints (padded 512 B)
    int* cntBatch = cntAll + 128;                       // 512 B
    float* acc4   = (float*)(base2 + 1024);             // 4*1024: S2,N2,S1,N1
    float* aLi    = acc4 + 4096;                        // 1024
    unsigned int* ticket = (unsigned int*)(aLi + 1024); // 1

    hipMemsetAsync(base2, 0, 1024 + 16384 + 4096 + 4, stream);
    prep_k<<<NCB + NHIST, 256, 0, stream>>>(feats, centers, labels, X2, cntAll, cntBatch);
    gemm_k<<<8 * 18 * 8, 256, 0, stream>>>(X2, labels, cntAll, cntBatch, sup,
                                           acc4, aLi, ticket, out);
}

// Round 7
// 158.099 us; speedup vs baseline: 2.0001x; 1.3748x over previous
//
#include <hip/hip_runtime.h>
#include <math.h>

#define KQ   32768
#define CC   100
#define BB   1024
#define DD   128
#define NTOT (BB + KQ)        // 33792
#define CB_CENT 1056
#define NCB  1060             // 32-row blocks in X2
#define NHIST 33              // histogram blocks (33*1024 = 33792)
#define NCG2 264              // branch-2 col groups (4 cb each)
#define NCG1 18               // branch-1 col groups (2 cb each); cg 264..281
#define CG_SUP 282            // sup-logits group
#define NCI  36               // ci range: ceil(283/8)

#define INV_T  14.285714285714286f
#define K2E    20.609929f     // INV_T * log2(e)
#define ALPHA  0.05f
#define EPSV   1e-12f

typedef __attribute__((ext_vector_type(8)))  short          short8;
typedef __attribute__((ext_vector_type(8)))  unsigned short ushort8;
typedef __attribute__((ext_vector_type(16))) float          float16;

__device__ __forceinline__ unsigned short f2bf_rne(float f) {
    unsigned int u = __float_as_uint(f);
    return (unsigned short)((u + 0x7FFFu + ((u >> 16) & 1u)) >> 16);
}

// X2 layout per 32-row block cb (8192 B): [ks 0..7][lane 0..63][16 B]
// element (row r, k): cb=r>>5, ks=k>>4, lane=(r&31)+32*((k>>3)&1), j=k&7
// == 32x32x16 MFMA A/B operand layout (verified R2-R6).

// ---------------- prep: convert+tile + parallel histogram ----------------
__global__ __launch_bounds__(256) void prep_k(const float* __restrict__ feats,
                                              const float* __restrict__ centers,
                                              const int* __restrict__ labels,
                                              unsigned short* __restrict__ X2,
                                              int* __restrict__ cntAll,
                                              int* __restrict__ cntBatch) {
    const int b = blockIdx.x, t = threadIdx.x;
    if (b >= NCB) {  // histogram blocks: LDS-local then one global atomic per bin
        __shared__ int hA[CC], hB[CC];
        if (t < CC) { hA[t] = 0; hB[t] = 0; }
        __syncthreads();
        const int base = (b - NCB) * 1024;
#pragma unroll
        for (int q = 0; q < 4; ++q) {
            int idx = base + q * 256 + t;
            int l = labels[idx];
            atomicAdd(&hA[l], 1);
            if (idx < BB) atomicAdd(&hB[l], 1);
        }
        __syncthreads();
        if (t < CC) {
            if (hA[t]) atomicAdd(&cntAll[t], hA[t]);
            if (hB[t]) atomicAdd(&cntBatch[t], hB[t]);
        }
        return;
    }
    __shared__ unsigned short sm[4096];   // 8 KB staging, layout == output block
    const int row = t >> 3, seg = t & 7;
    const int r = b * 32 + row;
    float v[16];
    if (r < NTOT) {
        const float4* p = (const float4*)&feats[(size_t)r * DD + seg * 16];
#pragma unroll
        for (int j = 0; j < 4; ++j) { float4 q = p[j]; v[4*j]=q.x; v[4*j+1]=q.y; v[4*j+2]=q.z; v[4*j+3]=q.w; }
    } else if (r < NTOT + CC) {
        const float4* p = (const float4*)&centers[(size_t)(r - NTOT) * DD + seg * 16];
#pragma unroll
        for (int j = 0; j < 4; ++j) { float4 q = p[j]; v[4*j]=q.x; v[4*j+1]=q.y; v[4*j+2]=q.z; v[4*j+3]=q.w; }
    } else {
#pragma unroll
        for (int j = 0; j < 16; ++j) v[j] = 0.f;
    }
    ushort8 H0, H1;
#pragma unroll
    for (int m = 0; m < 8; ++m) {
        H0[m] = f2bf_rne(v[m]);
        H1[m] = f2bf_rne(v[m + 8]);
    }
    *(ushort8*)&sm[seg * 512 + row * 8]        = H0;
    *(ushort8*)&sm[seg * 512 + (row + 32) * 8] = H1;
    __syncthreads();
    const ushort8* src = (const ushort8*)sm;
    ushort8* dst = (ushort8*)((char*)X2 + (size_t)b * 8192);
#pragma unroll
    for (int j = 0; j < 2; ++j) dst[j * 256 + t] = src[j * 256 + t];
}

// ---------------- one 32x32 tile: batched B loads -> MFMA chain -> epilogue ----------------
__device__ __forceinline__ void tile_cb(
    const char* Xb, int cb, int lc, float rn, float drm, bool checkDiag,
    int lane, int half, int ln, int growbase,
    const short8* Ah, const int* rlab, float* sS, float* sN)
{
    const size_t bbase = (size_t)cb * 8192 + (size_t)lane * 16;
    short8 B[8];
#pragma unroll
    for (int ks = 0; ks < 8; ++ks)
        B[ks] = *(const short8*)(Xb + bbase + (size_t)ks * 1024);   // MLP = 8
    float16 acc;
#pragma unroll
    for (int reg = 0; reg < 16; ++reg) acc[reg] = 0.f;
#pragma unroll
    for (int ks = 0; ks < 8; ++ks)
        acc = __builtin_amdgcn_mfma_f32_32x32x16_bf16(Ah[ks], B[ks], acc, 0, 0, 0);
    const int ccol = cb * 32 + ln;
#pragma unroll
    for (int reg = 0; reg < 16; ++reg) {
        int ro = (reg & 3) + 8 * (reg >> 2) + 4 * half;
        float a  = acc[reg];
        float mf = (lc == rlab[reg]) ? 1.f : 0.f;
        float wgt = fmaf(mf, drm, rn);
        if (checkDiag) {              // wave-uniform; at most 1 cb per block
            bool d = (ccol == growbase + ro);
            wgt = d ? 0.f : wgt;
            mf  = d ? 0.f : mf;
        }
        float e = exp2f(fmaf(a, K2E, -K2E));   // exp(raw - SHIFT)
        sS[reg] = fmaf(e, wgt, sS[reg]);
        sN[reg] = fmaf(mf, a, sN[reg]);        // un-scaled dot; *INV_T later
    }
}

// ---------------- fused GEMM + sup-sums ----------------
// grid 2304 = 8 xcd * 8 rt * 36 ci; cg = xcd + 8*ci.
// cg<264: branch2 (4 cb). 264..281: branch1 (2 cb). 282: sup sums. >282: idle.
__global__ __launch_bounds__(256) void gemm_k(
    const unsigned short* __restrict__ X2, const int* __restrict__ labels,
    const int* __restrict__ cntAll, const int* __restrict__ cntBatch,
    const float* __restrict__ sup, float* __restrict__ acc4,
    float* __restrict__ aLi) {
    const int b = blockIdx.x;
    const int xcd = b & 7, l = b >> 3;
    const int rt = l & 7, ci = l >> 3;
    const int cg = xcd + 8 * ci;
    if (cg > CG_SUP) return;

    const int tid = threadIdx.x;
    const int lane = tid & 63, w = tid >> 6;
    const int half = lane >> 5, ln = lane & 31;
    const char* Xb = (const char*)X2;

    if (cg == CG_SUP) {
        // sup-logits exp-sums, coalesced (lane = class), wave = 32 rows
        const int g = rt * 4 + w;
        const int c0 = lane;
        const int c1 = lane + 64;
        float n0 = (float)cntAll[c0];
        float rA0 = __builtin_amdgcn_rcpf(n0);
        float rAm0 = __builtin_amdgcn_rcpf(fmaxf(n0 - 1.f, 1.f));
        float rA1 = 0.f, rAm1 = 0.f;
        if (lane < 36) {
            float n1 = (float)cntAll[c1];
            rA1 = __builtin_amdgcn_rcpf(n1);
            rAm1 = __builtin_amdgcn_rcpf(fmaxf(n1 - 1.f, 1.f));
        }
        for (int rr = 0; rr < 32; ++rr) {
            int row = g * 32 + rr;
            int li = labels[row];
            const float* srow = &sup[(size_t)row * CC];
            float v0 = srow[c0];
            float s = __expf(v0 - INV_T) * ((c0 == li) ? rAm0 : rA0);
            float liv = (c0 == li) ? v0 : 0.f;
            if (lane < 36) {
                float v1 = srow[c1];
                s += __expf(v1 - INV_T) * ((c1 == li) ? rAm1 : rA1);
                liv += (c1 == li) ? v1 : 0.f;
            }
#pragma unroll
            for (int off = 1; off < 64; off <<= 1) {
                s += __shfl_xor(s, off, 64);
                liv += __shfl_xor(liv, off, 64);
            }
            if (lane == 0) {
                atomicAdd(&acc4[row], s);
                atomicAdd(&aLi[row], liv);
            }
        }
        return;
    }

    const int rb = rt * 4 + w;
    const int growbase = rt * 128 + w * 32;
    short8 Ah[8];
    {
        size_t abase = (size_t)rb * 8192 + (size_t)lane * 16;
#pragma unroll
        for (int ks = 0; ks < 8; ++ks)
            Ah[ks] = *(const short8*)(Xb + abase + (size_t)ks * 1024);
    }
    int rlab[16];
#pragma unroll
    for (int reg = 0; reg < 16; ++reg) {
        int ro = (reg & 3) + 8 * (reg >> 2) + 4 * half;
        rlab[reg] = labels[growbase + ro];
    }
    float sS[16], sN[16];
#pragma unroll
    for (int reg = 0; reg < 16; ++reg) { sS[reg] = 0.f; sN[reg] = 0.f; }

    const bool isB2 = (cg < NCG2);
    if (isB2) {
#pragma unroll
        for (int i = 0; i < 4; ++i) {
            const int cb = cg * 4 + i;
            int lc = labels[cb * 32 + ln];
            float c = (float)cntAll[lc];
            float rn = __builtin_amdgcn_rcpf(c);
            float drm = __builtin_amdgcn_rcpf(c - ALPHA) - rn;
            tile_cb(Xb, cb, lc, rn, drm, cb == rb,
                    lane, half, ln, growbase, Ah, rlab, sS, sN);
        }
    } else {
        const int t1 = cg - NCG2;   // 0..17
#pragma unroll
        for (int i = 0; i < 2; ++i) {
            const int cb = (t1 < 16) ? (t1 * 2 + i) : (CB_CENT + (t1 - 16) * 2 + i);
            const int ccol = cb * 32 + ln;
            int lc;
            if (t1 < 16) lc = labels[ccol];
            else { int c2 = ccol - NTOT; lc = (c2 < CC) ? c2 : -1; }
            int cbv = (lc >= 0) ? cntBatch[lc] : 0;
            float c1 = (float)(cbv + 1);
            float rn = (lc >= 0) ? __builtin_amdgcn_rcpf(c1) : 0.f;
            float rm = __builtin_amdgcn_rcpf(fmaxf(c1 - 1.f, 1.f));
            float drm = (lc >= 0) ? (rm - rn) : 0.f;
            tile_cb(Xb, cb, lc, rn, drm, (t1 < 16) && (cb == rb),
                    lane, half, ln, growbase, Ah, rlab, sS, sN);
        }
    }
    float* aS = isB2 ? acc4          : (acc4 + 2048);
    float* aN = isB2 ? (acc4 + 1024) : (acc4 + 3072);
#pragma unroll
    for (int reg = 0; reg < 16; ++reg) {
        float a = sS[reg], c = sN[reg];
#pragma unroll
        for (int off = 1; off < 32; off <<= 1) {
            a += __shfl_xor(a, off, 64);
            c += __shfl_xor(c, off, 64);
        }
        if (ln == 0) {
            int ro = (reg & 3) + 8 * (reg >> 2) + 4 * half;
            int grow = growbase + ro;
            atomicAdd(&aS[grow], a);
            atomicAdd(&aN[grow], c);
        }
    }
}

// ---------------- finalize: per-row loss + mean, one block ----------------
__global__ __launch_bounds__(1024) void finalize_k(
    const int* __restrict__ labels,
    const int* __restrict__ cntAll, const int* __restrict__ cntBatch,
    const float* __restrict__ acc4, const float* __restrict__ aLi,
    float* __restrict__ out) {
    const int t = threadIdx.x;
    const int li = labels[t];
    float S2 = acc4[t];
    float N2 = acc4[1024 + t] * INV_T;
    float S1 = acc4[2048 + t];
    float N1v = acc4[3072 + t] * INV_T;
    float sli = aLi[t];
    float cA = (float)cntAll[li];
    float msum2 = fmaf(ALPHA, cA - 1.f, 1.f);
    float loss2 = -(fmaf(ALPHA, N2, sli) / msum2 - INV_T - logf(S2 + EPSV));
    float loss1 = -(N1v / (float)cntBatch[li] - INV_T - logf(S1 + EPSV));
    float s = loss1 + loss2;
    __shared__ float buf[16];
#pragma unroll
    for (int off = 1; off < 64; off <<= 1) s += __shfl_xor(s, off, 64);
    if ((t & 63) == 0) buf[t >> 6] = s;
    __syncthreads();
    if (t < 64) {
        float x = (t < 16) ? buf[t] : 0.f;
#pragma unroll
        for (int off = 1; off < 16; off <<= 1) x += __shfl_xor(x, off, 64);
        if (t == 0) out[0] = x / (float)BB;
    }
}

extern "C" void kernel_launch(void* const* d_in, const int* in_sizes, int n_in,
                              void* d_out, int out_size, void* d_ws, size_t ws_size,
                              hipStream_t stream) {
    const float* feats   = (const float*)d_in[0];
    const float* sup     = (const float*)d_in[1];
    const float* centers = (const float*)d_in[2];
    const int*   labels  = (const int*)d_in[3];
    float* out = (float*)d_out;
    char*  wsb = (char*)d_ws;

    const size_t X2_BYTES = (size_t)NCB * 8192;         // 8,683,520
    unsigned short* X2 = (unsigned short*)wsb;
    char* base2 = wsb + X2_BYTES;
    int* cntAll   = (int*)base2;                        // 128 ints (padded 512 B)
    int* cntBatch = cntAll + 128;                       // 512 B
    float* acc4   = (float*)(base2 + 1024);             // 4*1024: S2,N2,S1,N1
    float* aLi    = acc4 + 4096;                        // 1024

    hipMemsetAsync(base2, 0, 1024 + 16384 + 4096, stream);
    prep_k<<<NCB + NHIST, 256, 0, stream>>>(feats, centers, labels, X2, cntAll, cntBatch);
    gemm_k<<<8 * 8 * NCI, 256, 0, stream>>>(X2, labels, cntAll, cntBatch, sup, acc4, aLi);
    finalize_k<<<1, 1024, 0, stream>>>(labels, cntAll, cntBatch, acc4, aLi, out);
}